// Round 10
// baseline (327.116 us; speedup 1.0000x reference)
//
#include <hip/hip_runtime.h>
#include <hip/hip_bf16.h>
#include <math.h>

#define B_   2
#define T_   2048
#define D_   2048
#define H_   16
#define HKV_ 4
#define DH_  128
#define RD_  64
#define KD_  (HKV_ * DH_)   // 512
#define SQKV 3072           // fused qkv row stride
#define VOFF 2560           // column offset of V in fused qkv output

typedef __attribute__((ext_vector_type(8))) short  short8;   // 8 x bf16
typedef __attribute__((ext_vector_type(4))) short  short4v;  // 4 x bf16
typedef __attribute__((ext_vector_type(4))) float  floatx4;  // MFMA C/D

__device__ __forceinline__ void async16(const __hip_bfloat16* g, __hip_bfloat16* l) {
  __builtin_amdgcn_global_load_lds(
      (const __attribute__((address_space(1))) void*)g,
      (__attribute__((address_space(3))) void*)l, 16, 0, 0);
}

__device__ __forceinline__ short bf16b(float x) {
  union { __hip_bfloat16 h; short s; } u;
  u.h = __float2bfloat16(x);
  return u.s;
}

// =====================================================================
// fused fp32 -> bf16 conversion
// =====================================================================
struct ConvArgs {
  const float* src[5];
  __hip_bfloat16* dst[5];
  int n[5];
};

__global__ __launch_bounds__(256) void conv_bf16(ConvArgs a) {
  const int arr = blockIdx.y;
  const int i = (blockIdx.x * 256 + threadIdx.x) * 8;
  if (i >= a.n[arr]) return;
  const float4 f1 = *(const float4*)(a.src[arr] + i);
  const float4 f2 = *(const float4*)(a.src[arr] + i + 4);
  union { short8 v; __hip_bfloat16 h[8]; } o;
  o.h[0] = __float2bfloat16(f1.x); o.h[1] = __float2bfloat16(f1.y);
  o.h[2] = __float2bfloat16(f1.z); o.h[3] = __float2bfloat16(f1.w);
  o.h[4] = __float2bfloat16(f2.x); o.h[5] = __float2bfloat16(f2.y);
  o.h[6] = __float2bfloat16(f2.z); o.h[7] = __float2bfloat16(f2.w);
  *(short8*)(a.dst[arr] + i) = o.v;
}

// =====================================================================
// QKV projection GEMM: 256x192 tiles, grid 16x16 = 256 blocks = one
// full uniform CU round. 8 waves (2M x 4N), wave tile 128x48, BK=32.
// RING-2 LDS (56 KiB -> 2 blocks/CU co-resident, was ring-3 84 KiB /
// 1 block): prefetch distance 1, stage of tile t+1 issued AFTER the
// boundary barrier of tile t (race-free: reads of t-1 from the same
// buffer complete before that barrier), vmcnt(0) drain at boundaries
// hidden by the co-resident block (m97/m114 mechanism). 2-phase
// m-half split with setprio (verified round 9: +6%).
// MODE 2: bf16 out; 16-col frags with col >= VOFF write TRANSPOSED
// into vt (B,HKV,DH,T), fusing transpose_v.
// =====================================================================
template <int MODE>
__global__ __launch_bounds__(512, 2) void gemm_192(const __hip_bfloat16* __restrict__ A,
                                                   const __hip_bfloat16* __restrict__ Bw,
                                                   void* __restrict__ Cout,
                                                   __hip_bfloat16* __restrict__ vtout,
                                                   int M, int N, int K, int nwg_x) {
  __shared__ __hip_bfloat16 ABs[2][28 * 512];  // panels 0..15 = A, 16..27 = B

  const int tid  = threadIdx.x;
  const int lane = tid & 63;
  const int w    = tid >> 6;           // 0..7
  const int wm   = w >> 2, wn = w & 3; // 2M x 4N wave grid
  const int quad = lane >> 4, m16 = lane & 15;

  // ---- bijective XCD swizzle (T1, m204 form) ----
  const int nwg = gridDim.x;
  const int q8  = nwg >> 3, r8 = nwg & 7;
  const int xcd = blockIdx.x & 7, o8 = blockIdx.x >> 3;
  const int swz = (xcd < r8 ? xcd * (q8 + 1) : r8 * (q8 + 1) + (xcd - r8) * q8) + o8;
  const int bx = swz % nwg_x, by = swz / nwg_x;
  const int bm = by * 256, bn = bx * 192;

  // ---- staging sources: wave w (w<7) stages panels w*4 .. w*4+3 ----
  const __hip_bfloat16* gp[4];
  int lp[4];
  if (w < 7) {
#pragma unroll
    for (int e = 0; e < 4; ++e) {
      const int p = w * 4 + e;               // 0..27
      lp[e] = p * 512;
      if (p < 16) gp[e] = A  + (size_t)(bm + p * 16 + m16) * K + quad * 8;
      else        gp[e] = Bw + (size_t)(bn + (p - 16) * 16 + m16) * K + quad * 8;
    }
  }

  const int nt = K >> 5;   // 64 K-tiles

  // ---- prologue: stage tile 0 into buffer 0 ----
  if (w < 7) {
#pragma unroll
    for (int e = 0; e < 4; ++e) async16(gp[e], &ABs[0][lp[e]]);
  }

  floatx4 acc[8][3] = {};
  const int fragoff = (quad * 16 + m16) * 8;   // linear-lane LDS read (0 conflicts)

  for (int t = 0; t < nt; ++t) {
    const int cur = t & 1, stg = cur ^ 1;
    // boundary: drain tile t's loads (and own stage writes), then sync.
    asm volatile("s_waitcnt vmcnt(0)" ::: "memory");
    __builtin_amdgcn_s_barrier();
    __builtin_amdgcn_sched_barrier(0);

    const __hip_bfloat16* base = &ABs[cur][0];
    const bool doStage = (w < 7) && (t + 1 < nt);
    const size_t ko = (size_t)(t + 1) * 32;

    // ================= phase A (m-half 0) =================
    short8 a0[4], b[3];
#pragma unroll
    for (int i = 0; i < 4; ++i)
      a0[i] = *(const short8*)(base + (wm * 8 + i) * 512 + fragoff);
#pragma unroll
    for (int j = 0; j < 3; ++j)
      b[j] = *(const short8*)(base + (16 + wn * 3 + j) * 512 + fragoff);
    if (doStage) {
      async16(gp[0] + ko, &ABs[stg][lp[0]]);
      async16(gp[1] + ko, &ABs[stg][lp[1]]);
    }
    __builtin_amdgcn_s_barrier();
    __builtin_amdgcn_sched_barrier(0);
    __builtin_amdgcn_s_setprio(1);
#pragma unroll
    for (int i = 0; i < 4; ++i)
#pragma unroll
      for (int j = 0; j < 3; ++j)
        acc[i][j] = __builtin_amdgcn_mfma_f32_16x16x32_bf16(a0[i], b[j], acc[i][j], 0, 0, 0);
    __builtin_amdgcn_s_setprio(0);
    __builtin_amdgcn_s_barrier();
    __builtin_amdgcn_sched_barrier(0);

    // ================= phase B (m-half 1) =================
    short8 a1[4];
#pragma unroll
    for (int i = 0; i < 4; ++i)
      a1[i] = *(const short8*)(base + (wm * 8 + 4 + i) * 512 + fragoff);
    if (doStage) {
      async16(gp[2] + ko, &ABs[stg][lp[2]]);
      async16(gp[3] + ko, &ABs[stg][lp[3]]);
    }
    __builtin_amdgcn_s_barrier();
    __builtin_amdgcn_sched_barrier(0);
    __builtin_amdgcn_s_setprio(1);
#pragma unroll
    for (int i = 0; i < 4; ++i)
#pragma unroll
      for (int j = 0; j < 3; ++j)
        acc[4 + i][j] = __builtin_amdgcn_mfma_f32_16x16x32_bf16(a1[i], b[j], acc[4 + i][j], 0, 0, 0);
    __builtin_amdgcn_s_setprio(0);
    // trailing barrier provided by next boundary
  }

  // ---- epilogue: per-16-col-frag K/V routing (VOFF is 16-aligned) ----
#pragma unroll
  for (int mt = 0; mt < 8; ++mt)
#pragma unroll
    for (int j = 0; j < 3; ++j) {
      const int col0 = bn + wn * 48 + j * 16;
      const int row0 = bm + wm * 128 + mt * 16 + quad * 4;
      if (MODE == 2 && col0 >= VOFF) {       // V frag: transposed write
        const int dh = col0 + m16 - VOFF;    // 0..511
        const int bb = row0 >> 11, t0 = row0 & (T_ - 1);
        short4v pk;
#pragma unroll
        for (int reg = 0; reg < 4; ++reg) pk[reg] = bf16b(acc[mt][j][reg]);
        *(short4v*)&vtout[((size_t)(bb * HKV_ + (dh >> 7)) * DH_ + (dh & 127)) * T_ + t0] = pk;
      } else {
#pragma unroll
        for (int reg = 0; reg < 4; ++reg) {
          const int row = row0 + reg;
          const int col = col0 + m16;
          if (MODE == 0)
            ((float*)Cout)[(size_t)row * N + col] = acc[mt][j][reg];
          else
            ((__hip_bfloat16*)Cout)[(size_t)row * N + col] = __float2bfloat16(acc[mt][j][reg]);
        }
      }
    }
}

// =====================================================================
// AO projection GEMM: BM=128 x BN=256 tiles -> 256 blocks = full fill.
// Ring-3 + counted vmcnt(3); one 16-MFMA phase per K-tile. fp32 out.
// =====================================================================
__global__ __launch_bounds__(512, 2) void gemm_k1(const __hip_bfloat16* __restrict__ A,
                                                  const __hip_bfloat16* __restrict__ Bw,
                                                  float* __restrict__ Cout,
                                                  int M, int N, int K, int nwg_x) {
  __shared__ __hip_bfloat16 As[3][8 * 512];    // 8 panels (128 rows x 32 k)
  __shared__ __hip_bfloat16 Bs[3][16 * 512];   // 16 panels (256 cols x 32 k)

  const int tid  = threadIdx.x;
  const int lane = tid & 63;
  const int w    = tid >> 6;           // 0..7
  const int wm   = w >> 2, wn = w & 3; // wave tile 64x64
  const int quad = lane >> 4, m16 = lane & 15;

  const int nwg = gridDim.x;
  const int q8  = nwg >> 3, r8 = nwg & 7;
  const int xcd = blockIdx.x & 7, o8 = blockIdx.x >> 3;
  const int swz = (xcd < r8 ? xcd * (q8 + 1) : r8 * (q8 + 1) + (xcd - r8) * q8) + o8;
  const int bx = swz % nwg_x, by = swz / nwg_x;
  const int bm = by * 128, bn = bx * 256;

  const __hip_bfloat16* gA  = A  + (size_t)(bm + w * 16 + m16) * K + quad * 8;
  const __hip_bfloat16* gB0 = Bw + (size_t)(bn + (w * 2 + 0) * 16 + m16) * K + quad * 8;
  const __hip_bfloat16* gB1 = Bw + (size_t)(bn + (w * 2 + 1) * 16 + m16) * K + quad * 8;

  const int nt = K >> 5;

  async16(gA,       &As[0][w * 512]);
  async16(gB0,      &Bs[0][(w * 2 + 0) * 512]);
  async16(gB1,      &Bs[0][(w * 2 + 1) * 512]);
  async16(gA + 32,  &As[1][w * 512]);
  async16(gB0 + 32, &Bs[1][(w * 2 + 0) * 512]);
  async16(gB1 + 32, &Bs[1][(w * 2 + 1) * 512]);

  floatx4 acc[4][4] = {};
  const int fragoff = (quad * 16 + m16) * 8;

  int cur = 0, stg = 2;
  for (int t = 0; t < nt; ++t) {
    if (t < nt - 1) asm volatile("s_waitcnt vmcnt(3)" ::: "memory");
    else            asm volatile("s_waitcnt vmcnt(0)" ::: "memory");
    __builtin_amdgcn_s_barrier();
    __builtin_amdgcn_sched_barrier(0);

    const __hip_bfloat16* abase = &As[cur][0];
    const __hip_bfloat16* bbase = &Bs[cur][0];

    short8 a[4], b[4];
#pragma unroll
    for (int i = 0; i < 4; ++i) {
      a[i] = *(const short8*)(abase + (wm * 4 + i) * 512 + fragoff);
      b[i] = *(const short8*)(bbase + (wn * 4 + i) * 512 + fragoff);
    }
    if (t + 2 < nt) {
      const size_t ko = (size_t)(t + 2) * 32;
      async16(gA + ko,  &As[stg][w * 512]);
      async16(gB0 + ko, &Bs[stg][(w * 2 + 0) * 512]);
      async16(gB1 + ko, &Bs[stg][(w * 2 + 1) * 512]);
    }
    __builtin_amdgcn_s_setprio(1);
#pragma unroll
    for (int i = 0; i < 4; ++i)
#pragma unroll
      for (int j = 0; j < 4; ++j)
        acc[i][j] = __builtin_amdgcn_mfma_f32_16x16x32_bf16(a[i], b[j], acc[i][j], 0, 0, 0);
    __builtin_amdgcn_s_setprio(0);

    cur = (cur == 2) ? 0 : cur + 1;
    stg = (stg == 2) ? 0 : stg + 1;
  }

#pragma unroll
  for (int mi = 0; mi < 4; ++mi)
#pragma unroll
    for (int nj = 0; nj < 4; ++nj)
#pragma unroll
      for (int reg = 0; reg < 4; ++reg) {
        const int row = bm + wm * 64 + mi * 16 + quad * 4 + reg;
        const int col = bn + wn * 64 + nj * 16 + m16;
        Cout[(size_t)row * N + col] = acc[mi][nj][reg];
      }
}

// =====================================================================
// Fused RoPE for q and k heads in one launch.
// =====================================================================
__global__ __launch_bounds__(256) void rope_qk(__hip_bfloat16* __restrict__ qkv,
                                               const float* __restrict__ cosT,
                                               const float* __restrict__ sinT,
                                               const float* __restrict__ temp,
                                               float inv_sqrt_dh) {
  const int unit = blockIdx.x * 4 + (threadIdx.x >> 6);
  const int lane = threadIdx.x & 63;
  const int M = B_ * T_;
  int bt, off;
  float scale;
  if (unit < M * H_) {
    const int h = unit % H_;
    bt = unit / H_;
    off = h * DH_;
    scale = temp[h] * inv_sqrt_dh;
  } else {
    const int u2 = unit - M * H_;
    const int h = u2 % HKV_;
    bt = u2 / HKV_;
    off = D_ + h * DH_;
    scale = 1.0f;
  }
  const int t = bt & (T_ - 1);
  __hip_bfloat16* p = qkv + (size_t)bt * SQKV + off;
  if (lane < 32) {
    const float x1 = __bfloat162float(p[2 * lane]);
    const float x2 = __bfloat162float(p[2 * lane + 1]);
    const float c = cosT[t * (RD_ / 2) + lane];
    const float s = sinT[t * (RD_ / 2) + lane];
    p[2 * lane]     = __float2bfloat16((x1 * c - x2 * s) * scale);
    p[2 * lane + 1] = __float2bfloat16((x1 * s + x2 * c) * scale);
  } else {
    const int d0 = RD_ + (lane - 32) * 2;
    p[d0]     = __float2bfloat16(__bfloat162float(p[d0]) * scale);
    p[d0 + 1] = __float2bfloat16(__bfloat162float(p[d0 + 1]) * scale);
  }
}

// =====================================================================
// Head-fused flash attention, transpose-form, 32-row q-tiles.
// KEY-SPLIT waves: 8 waves = 4 heads x 2 key-halves (round-6 verified
// form; PV on 16x16x16_1k — the x32+shfl variant measured neutral-to-
// negative in round 9 and was reverted).
// =====================================================================
__global__ __launch_bounds__(512, 2) void flash_attn_t2(
    const __hip_bfloat16* __restrict__ qkv,  // [B*T][SQKV]
    const __hip_bfloat16* __restrict__ vt,   // [B][HKV][DH][T]
    __hip_bfloat16* __restrict__ ao) {       // [B*T][D]
  // [buf][ K: 0..8191 | V: 8192..16383 ]  (64 KiB total, reused as
  // fp32 scratch for the cross-wave reduction after the main loop)
  __shared__ __hip_bfloat16 KV[2][16384];

  const int tid = threadIdx.x, lane = tid & 63, w = tid >> 6;   // w 0..7
  const int quad = lane >> 4, m16 = lane & 15;

  const int bid = blockIdx.x;
  const int g = bid & 7;                    // (b,kvh) group -> XCD affinity
  const int b = g >> 2, kvh = g & 3;
  const int u = bid >> 3;                   // 0..63
  const int qt = 63 - u;                    // heavy first (LPT)
  const int hw = w & 3;                     // head-within-group
  const int khalf = w >> 2;                 // 0/1: which 32-key half
  const int h = kvh * 4 + hw;
  const int qRow0 = qt * 32;
  const int ktEnd = (qt >> 1) + 1;          // 1..32 slabs of 64 keys

  const size_t bT = (size_t)b * T_;

  // Q fragments (B-operand layout): 2 row-tiles x 4 dh-steps
  short8 qa[2][4];
#pragma unroll
  for (int qi = 0; qi < 2; qi++) {
    const __hip_bfloat16* qp = qkv + (bT + qRow0 + qi * 16 + m16) * SQKV + h * DH_;
#pragma unroll
    for (int ks = 0; ks < 4; ks++) qa[qi][ks] = *(const short8*)(qp + ks * 32 + quad * 8);
  }

  const short one = (short)0x3F80;
  const short4v ones4 = {one, one, one, one};

  // staging pointers: 8 waves x 2 issues cover the 16 panels of K and V
  const __hip_bfloat16* kptr[2];
  const __hip_bfloat16* vptr[2];
#pragma unroll
  for (int e = 0; e < 2; e++) {
    const int I = w * 2 + e;                 // 0..15
    const int panelK = I >> 2, kcK = (I & 3) * 4 + quad;
    kptr[e] = qkv + D_ + (bT + panelK * 16 + m16) * SQKV + kvh * DH_ + kcK * 8;
    const int panelV = I >> 1, tc = (I & 1) * 4 + quad;
    vptr[e] = vt + ((size_t)(b * HKV_ + kvh) * DH_ + panelV * 16 + m16) * T_ + tc * 8;
  }

  // prologue: stage slab 0 into buffer 0
#pragma unroll
  for (int e = 0; e < 2; e++) {
    const int I = w * 2 + e;
    async16(kptr[e], &KV[0][I * 512]);
    async16(vptr[e], &KV[0][8192 + I * 512]);
    kptr[e] += (size_t)64 * SQKV;
    vptr[e] += 64;
  }

  floatx4 ot[8][2] = {};   // partial O^T [dh-tile][qrow-tile]
  floatx4 lt[2] = {};      // partial l   [qrow-tile]

  for (int kt = 0; kt < ktEnd; kt++) {
    const int cur = kt & 1;
    __syncthreads();       // drains cur-slab loads; prev reads of nxt done
    if (kt + 1 < ktEnd) {
      const int nxt = cur ^ 1;
#pragma unroll
      for (int e = 0; e < 2; e++) {
        const int I = w * 2 + e;
        async16(kptr[e], &KV[nxt][I * 512]);
        async16(vptr[e], &KV[nxt][8192 + I * 512]);
        kptr[e] += (size_t)64 * SQKV;
        vptr[e] += 64;
      }
    }

    const bool last = (kt == ktEnd - 1);
    // qt even: khalf=1 half of the diagonal slab is fully masked -> skip
    if (last && khalf == 1 && ((qt & 1) == 0)) continue;

    // ---- S^T = K Q^T  (this wave's 32 keys x 32 qrows) ----
    floatx4 st[2][2] = {};  // [ki=key-16-tile within half][qi]
#pragma unroll
    for (int ki = 0; ki < 2; ki++) {
      const int kg = khalf * 2 + ki;        // global key-16-tile 0..3
#pragma unroll
      for (int ks = 0; ks < 4; ks++) {
        const int unit = kg * 256 + (ks * 4 + quad) * 16 + m16;
        const short8 kf = *(const short8*)&KV[cur][unit * 8];
#pragma unroll
        for (int qi = 0; qi < 2; qi++)
          st[ki][qi] = __builtin_amdgcn_mfma_f32_16x16x32_bf16(kf, qa[qi][ks],
                                                               st[ki][qi], 0, 0, 0);
      }
    }

    // ---- causal mask: only the matching 32-range needs it ----
    if (last && khalf == (qt & 1)) {
#pragma unroll
      for (int ki = 0; ki < 2; ki++)
#pragma unroll
        for (int qi = 0; qi < 2; qi++) {
          const int rowg = qRow0 + qi * 16 + m16;
#pragma unroll
          for (int reg = 0; reg < 4; reg++) {
            const int keyg = kt * 64 + khalf * 32 + ki * 16 + quad * 4 + reg;
            if (keyg > rowg) st[ki][qi][reg] = -1e30f;
          }
        }
    }

    // ---- P^T = exp(S^T), packed: C-tile == 16x16x16 B-frag ----
    short4v pf[2][2];
#pragma unroll
    for (int ki = 0; ki < 2; ki++)
#pragma unroll
      for (int qi = 0; qi < 2; qi++) {
        short4v t;
#pragma unroll
        for (int reg = 0; reg < 4; reg++) t[reg] = bf16b(__expf(st[ki][qi][reg]));
        pf[ki][qi] = t;
      }

    // ---- O^T += V^T P^T ; l += ones P^T  (partial over this key half) ----
#pragma unroll
    for (int mi = 0; mi < 8; mi++)
#pragma unroll
      for (int ki = 0; ki < 2; ki++) {
        const int kg = khalf * 2 + ki;
        const int unit = mi * 128 + (kg * 2 + (quad >> 1)) * 16 + m16;
        const short4v vf = *(const short4v*)&KV[cur][8192 + unit * 8 + (quad & 1) * 4];
#pragma unroll
        for (int qi = 0; qi < 2; qi++)
          ot[mi][qi] = __builtin_amdgcn_mfma_f32_16x16x16bf16_1k(vf, pf[ki][qi],
                                                                 ot[mi][qi], 0, 0, 0);
      }
#pragma unroll
    for (int ki = 0; ki < 2; ki++)
#pragma unroll
      for (int qi = 0; qi < 2; qi++)
        lt[qi] = __builtin_amdgcn_mfma_f32_16x16x16bf16_1k(ones4, pf[ki][qi],
                                                           lt[qi], 0, 0, 0);
  }

  // ---- cross-wave reduction (khalf pairs) via retired KV buffers ----
  floatx4* scr = (floatx4*)&KV[0][0];   // 4096 slots of 16B
  __syncthreads();                      // all slab reads of KV done
  if (khalf == 1) {                     // round 1: mi 0..5
#pragma unroll
    for (int mi = 0; mi < 6; mi++)
#pragma unroll
      for (int qi = 0; qi < 2; qi++)
        scr[((hw * 6 + mi) * 2 + qi) * 64 + lane] = ot[mi][qi];
  }
  __syncthreads();
  if (khalf == 0) {
#pragma unroll
    for (int mi = 0; mi < 6; mi++)
#pragma unroll
      for (int qi = 0; qi < 2; qi++)
        ot[mi][qi] += scr[((hw * 6 + mi) * 2 + qi) * 64 + lane];
  }
  __syncthreads();
  if (khalf == 1) {                     // round 2: mi 6..7 + lt
#pragma unroll
    for (int j = 0; j < 2; j++)
#pragma unroll
      for (int qi = 0; qi < 2; qi++)
        scr[((hw * 2 + j) * 2 + qi) * 64 + lane] = ot[6 + j][qi];
#pragma unroll
    for (int qi = 0; qi < 2; qi++)
      scr[1024 + (hw * 2 + qi) * 64 + lane] = lt[qi];
  }
  __syncthreads();
  if (khalf == 0) {
#pragma unroll
    for (int j = 0; j < 2; j++)
#pragma unroll
      for (int qi = 0; qi < 2; qi++)
        ot[6 + j][qi] += scr[((hw * 2 + j) * 2 + qi) * 64 + lane];
#pragma unroll
    for (int qi = 0; qi < 2; qi++)
      lt[qi] += scr[1024 + (hw * 2 + qi) * 64 + lane];

    // ---- epilogue: O^T C-layout -> packed b64 row-stores ----
#pragma unroll
    for (int qi = 0; qi < 2; qi++) {
      const float inv = 1.0f / lt[qi][0];   // all regs equal = l[qrow]
      const size_t gr = (bT + qRow0 + qi * 16 + m16) * D_ + h * DH_;
#pragma unroll
      for (int mi = 0; mi < 8; mi++) {
        short4v o;
#pragma unroll
        for (int reg = 0; reg < 4; reg++) o[reg] = bf16b(ot[mi][qi][reg] * inv);
        *(short4v*)&ao[gr + mi * 16 + quad * 4] = o;
      }
    }
  }
}

// =====================================================================
// Launch
// =====================================================================
extern "C" void kernel_launch(void* const* d_in, const int* in_sizes, int n_in,
                              void* d_out, int out_size, void* d_ws, size_t ws_size,
                              hipStream_t stream) {
  const float* x    = (const float*)d_in[0];
  const float* cosT = (const float*)d_in[1];
  const float* sinT = (const float*)d_in[2];
  const float* Wq   = (const float*)d_in[3];
  const float* Wk   = (const float*)d_in[4];
  const float* Wv   = (const float*)d_in[5];
  const float* Wo   = (const float*)d_in[6];
  const float* temp = (const float*)d_in[7];
  float* out = (float*)d_out;

  const int M = B_ * T_;                     // 4096
  const size_t XN   = (size_t)M * D_;
  const size_t WQN  = (size_t)D_ * D_;
  const size_t WKN  = (size_t)KD_ * D_;
  const size_t QKVN = (size_t)M * SQKV;
  const size_t KN   = (size_t)M * KD_;

  __hip_bfloat16* ws = (__hip_bfloat16*)d_ws;
  __hip_bfloat16* xb    = ws;  ws += XN;
  __hip_bfloat16* wqkvb = ws;  ws += WQN + 2 * WKN;
  __hip_bfloat16* wob   = ws;  ws += WQN;
  __hip_bfloat16* qkvb  = ws;  ws += QKVN;
  __hip_bfloat16* vtb   = ws;  ws += KN;
  __hip_bfloat16* aob   = ws;  ws += XN;

  dim3 blk(256);

  ConvArgs ca;
  ca.src[0] = x;  ca.dst[0] = xb;                  ca.n[0] = (int)XN;
  ca.src[1] = Wq; ca.dst[1] = wqkvb;               ca.n[1] = (int)WQN;
  ca.src[2] = Wk; ca.dst[2] = wqkvb + WQN;         ca.n[2] = (int)WKN;
  ca.src[3] = Wv; ca.dst[3] = wqkvb + WQN + WKN;   ca.n[3] = (int)WKN;
  ca.src[4] = Wo; ca.dst[4] = wob;                 ca.n[4] = (int)WQN;
  conv_bf16<<<dim3(4096, 5), blk, 0, stream>>>(ca);

  // fused QKV projection (256x192 tiles, 16x16 = 256 blocks = one full
  // uniform CU round, ring-2 -> 2 blocks/CU); v-col frags -> vtb transposed
  gemm_192<2><<<dim3((SQKV / 192) * (M / 256)), dim3(512), 0, stream>>>(
      xb, wqkvb, qkvb, vtb, M, SQKV, D_, SQKV / 192);

  const float inv_sqrt_dh = 1.0f / sqrtf((float)DH_);
  rope_qk<<<(M * (H_ + HKV_)) / 4, blk, 0, stream>>>(qkvb, cosT, sinT, temp, inv_sqrt_dh);

  // 512 blocks x 512 threads (8 waves: 4 heads x 2 key-halves)
  flash_attn_t2<<<512, dim3(512), 0, stream>>>(qkvb, vtb, aob);

  // output projection (128x256 tiles, 256 blocks = full CU fill)
  gemm_k1<<<dim3((D_ / 256) * (M / 128)), dim3(512), 0, stream>>>(
      aob, wob, out, M, D_, D_, D_ / 256);
}

// Round 11
// 295.760 us; speedup vs baseline: 1.1060x; 1.1060x over previous
//
#include <hip/hip_runtime.h>
#include <hip/hip_bf16.h>
#include <math.h>

#define B_   2
#define T_   2048
#define D_   2048
#define H_   16
#define HKV_ 4
#define DH_  128
#define RD_  64
#define KD_  (HKV_ * DH_)   // 512
#define SQKV 3072           // fused qkv row stride
#define VOFF 2560           // column offset of V in fused qkv output

typedef __attribute__((ext_vector_type(8))) short  short8;   // 8 x bf16
typedef __attribute__((ext_vector_type(4))) short  short4v;  // 4 x bf16
typedef __attribute__((ext_vector_type(4))) float  floatx4;  // MFMA C/D

__device__ __forceinline__ void async16(const __hip_bfloat16* g, __hip_bfloat16* l) {
  __builtin_amdgcn_global_load_lds(
      (const __attribute__((address_space(1))) void*)g,
      (__attribute__((address_space(3))) void*)l, 16, 0, 0);
}

__device__ __forceinline__ short bf16b(float x) {
  union { __hip_bfloat16 h; short s; } u;
  u.h = __float2bfloat16(x);
  return u.s;
}

// =====================================================================
// fused fp32 -> bf16 conversion
// =====================================================================
struct ConvArgs {
  const float* src[5];
  __hip_bfloat16* dst[5];
  int n[5];
};

__global__ __launch_bounds__(256) void conv_bf16(ConvArgs a) {
  const int arr = blockIdx.y;
  const int i = (blockIdx.x * 256 + threadIdx.x) * 8;
  if (i >= a.n[arr]) return;
  const float4 f1 = *(const float4*)(a.src[arr] + i);
  const float4 f2 = *(const float4*)(a.src[arr] + i + 4);
  union { short8 v; __hip_bfloat16 h[8]; } o;
  o.h[0] = __float2bfloat16(f1.x); o.h[1] = __float2bfloat16(f1.y);
  o.h[2] = __float2bfloat16(f1.z); o.h[3] = __float2bfloat16(f1.w);
  o.h[4] = __float2bfloat16(f2.x); o.h[5] = __float2bfloat16(f2.y);
  o.h[6] = __float2bfloat16(f2.z); o.h[7] = __float2bfloat16(f2.w);
  *(short8*)(a.dst[arr] + i) = o.v;
}

// =====================================================================
// QKV projection GEMM: 256x192 tiles, grid 16x16 = 256 blocks = one
// full uniform CU round. 8 waves (2M x 4N), wave tile 128x48, BK=32.
// RING-3 (round-9 verified 67.9us: 84 KiB, prefetch distance 2,
// counted vmcnt(4) at K-tile boundaries — ring-2 experiment reverted:
// grid==256 means 1 block/CU, co-residency can never materialize).
// 2-phase m-half split with setprio (verified +6%).
// NEW: RoPE + temp/sqrt(dh) scaling FUSED into the epilogue (replaces
// the rope_qk kernel; saves ~50 MB of qkv re-read/re-write traffic).
// Pair partner col^1 lives in lane^1 (same quad): one shfl_xor.
// MODE 2: bf16 out; 16-col frags with col >= VOFF write TRANSPOSED
// into vt (B,HKV,DH,T), fusing transpose_v.
// =====================================================================
template <int MODE>
__global__ __launch_bounds__(512, 1) void gemm_192(const __hip_bfloat16* __restrict__ A,
                                                   const __hip_bfloat16* __restrict__ Bw,
                                                   void* __restrict__ Cout,
                                                   __hip_bfloat16* __restrict__ vtout,
                                                   const float* __restrict__ cosT,
                                                   const float* __restrict__ sinT,
                                                   const float* __restrict__ temp,
                                                   float inv_sqrt_dh,
                                                   int M, int N, int K, int nwg_x) {
  __shared__ __hip_bfloat16 ABs[3][28 * 512];  // panels 0..15 = A, 16..27 = B

  const int tid  = threadIdx.x;
  const int lane = tid & 63;
  const int w    = tid >> 6;           // 0..7
  const int wm   = w >> 2, wn = w & 3; // 2M x 4N wave grid
  const int quad = lane >> 4, m16 = lane & 15;

  // ---- bijective XCD swizzle (T1, m204 form) ----
  const int nwg = gridDim.x;
  const int q8  = nwg >> 3, r8 = nwg & 7;
  const int xcd = blockIdx.x & 7, o8 = blockIdx.x >> 3;
  const int swz = (xcd < r8 ? xcd * (q8 + 1) : r8 * (q8 + 1) + (xcd - r8) * q8) + o8;
  const int bx = swz % nwg_x, by = swz / nwg_x;
  const int bm = by * 256, bn = bx * 192;

  // ---- staging sources: wave w (w<7) stages panels w*4 .. w*4+3 ----
  const __hip_bfloat16* gp[4];
  int lp[4];
  if (w < 7) {
#pragma unroll
    for (int e = 0; e < 4; ++e) {
      const int p = w * 4 + e;               // 0..27
      lp[e] = p * 512;
      if (p < 16) gp[e] = A  + (size_t)(bm + p * 16 + m16) * K + quad * 8;
      else        gp[e] = Bw + (size_t)(bn + (p - 16) * 16 + m16) * K + quad * 8;
    }
  }

  const int nt = K >> 5;   // 64 K-tiles

  // ---- prologue: stage tiles 0 and 1 ----
  if (w < 7) {
#pragma unroll
    for (int e = 0; e < 4; ++e) async16(gp[e],      &ABs[0][lp[e]]);
#pragma unroll
    for (int e = 0; e < 4; ++e) async16(gp[e] + 32, &ABs[1][lp[e]]);
  }

  floatx4 acc[8][3] = {};
  const int fragoff = (quad * 16 + m16) * 8;   // linear-lane LDS read (0 conflicts)

  int cur = 0, stg = 2;
  for (int t = 0; t < nt; ++t) {
    // counted wait: tile t+1's 4 loads stay in flight (per-wave count)
    if (t < nt - 1) asm volatile("s_waitcnt vmcnt(4)" ::: "memory");
    else            asm volatile("s_waitcnt vmcnt(0)" ::: "memory");
    __builtin_amdgcn_s_barrier();
    __builtin_amdgcn_sched_barrier(0);

    const __hip_bfloat16* base = &ABs[cur][0];
    const bool doStage = (w < 7) && (t + 2 < nt);
    const size_t ko = (size_t)(t + 2) * 32;

    // ================= phase A (m-half 0) =================
    short8 a0[4], b[3];
#pragma unroll
    for (int i = 0; i < 4; ++i)
      a0[i] = *(const short8*)(base + (wm * 8 + i) * 512 + fragoff);
#pragma unroll
    for (int j = 0; j < 3; ++j)
      b[j] = *(const short8*)(base + (16 + wn * 3 + j) * 512 + fragoff);
    if (doStage) {
      async16(gp[0] + ko, &ABs[stg][lp[0]]);
      async16(gp[1] + ko, &ABs[stg][lp[1]]);
    }
    __builtin_amdgcn_s_barrier();
    __builtin_amdgcn_sched_barrier(0);
    __builtin_amdgcn_s_setprio(1);
#pragma unroll
    for (int i = 0; i < 4; ++i)
#pragma unroll
      for (int j = 0; j < 3; ++j)
        acc[i][j] = __builtin_amdgcn_mfma_f32_16x16x32_bf16(a0[i], b[j], acc[i][j], 0, 0, 0);
    __builtin_amdgcn_s_setprio(0);
    __builtin_amdgcn_s_barrier();
    __builtin_amdgcn_sched_barrier(0);

    // ================= phase B (m-half 1) =================
    short8 a1[4];
#pragma unroll
    for (int i = 0; i < 4; ++i)
      a1[i] = *(const short8*)(base + (wm * 8 + 4 + i) * 512 + fragoff);
    if (doStage) {
      async16(gp[2] + ko, &ABs[stg][lp[2]]);
      async16(gp[3] + ko, &ABs[stg][lp[3]]);
    }
    __builtin_amdgcn_s_barrier();
    __builtin_amdgcn_sched_barrier(0);
    __builtin_amdgcn_s_setprio(1);
#pragma unroll
    for (int i = 0; i < 4; ++i)
#pragma unroll
      for (int j = 0; j < 3; ++j)
        acc[4 + i][j] = __builtin_amdgcn_mfma_f32_16x16x32_bf16(a1[i], b[j], acc[4 + i][j], 0, 0, 0);
    __builtin_amdgcn_s_setprio(0);
    // trailing barrier provided by next boundary

    cur = (cur == 2) ? 0 : cur + 1;
    stg = (stg == 2) ? 0 : stg + 1;
  }

  // ---- epilogue: per-16-col-frag routing + fused RoPE/scale ----
#pragma unroll
  for (int mt = 0; mt < 8; ++mt)
#pragma unroll
    for (int j = 0; j < 3; ++j) {
      const int col0 = bn + wn * 48 + j * 16;       // wave-uniform
      const int row0 = bm + wm * 128 + mt * 16 + quad * 4;
      if (MODE == 2 && col0 >= VOFF) {              // V frag: transposed write
        const int dh = col0 + m16 - VOFF;           // 0..511
        const int bb = row0 >> 11, t0 = row0 & (T_ - 1);
        short4v pk;
#pragma unroll
        for (int reg = 0; reg < 4; ++reg) pk[reg] = bf16b(acc[mt][j][reg]);
        *(short4v*)&vtout[((size_t)(bb * HKV_ + (dh >> 7)) * DH_ + (dh & 127)) * T_ + t0] = pk;
      } else {
        float vals[4];
#pragma unroll
        for (int reg = 0; reg < 4; ++reg) vals[reg] = acc[mt][j][reg];
        if (MODE == 2) {
          const bool isQ   = (col0 < D_);
          const float scale = isQ ? temp[col0 >> 7] * inv_sqrt_dh : 1.0f;
          if ((col0 & 127) < 64) {                  // rope-active frag (uniform)
            const int iidx = ((col0 & 127) + m16) >> 1;        // 0..31
            const float sgn = (m16 & 1) ? 1.0f : -1.0f;
#pragma unroll
            for (int reg = 0; reg < 4; ++reg) {
              const int t0 = (row0 + reg) & (T_ - 1);
              const float c = cosT[t0 * (RD_ / 2) + iidx];
              const float s = sinT[t0 * (RD_ / 2) + iidx];
              const float other = __shfl_xor(vals[reg], 1, 64);
              vals[reg] = vals[reg] * c + sgn * other * s;
            }
          }
          if (isQ) {
#pragma unroll
            for (int reg = 0; reg < 4; ++reg) vals[reg] *= scale;
          }
        }
#pragma unroll
        for (int reg = 0; reg < 4; ++reg) {
          const int row = row0 + reg;
          const int col = col0 + m16;
          if (MODE == 0)
            ((float*)Cout)[(size_t)row * N + col] = vals[reg];
          else
            ((__hip_bfloat16*)Cout)[(size_t)row * N + col] = __float2bfloat16(vals[reg]);
        }
      }
    }
}

// =====================================================================
// AO projection GEMM: BM=128 x BN=256 tiles -> 256 blocks = full fill.
// Ring-3 + counted vmcnt(3); one 16-MFMA phase per K-tile. fp32 out.
// =====================================================================
__global__ __launch_bounds__(512, 2) void gemm_k1(const __hip_bfloat16* __restrict__ A,
                                                  const __hip_bfloat16* __restrict__ Bw,
                                                  float* __restrict__ Cout,
                                                  int M, int N, int K, int nwg_x) {
  __shared__ __hip_bfloat16 As[3][8 * 512];    // 8 panels (128 rows x 32 k)
  __shared__ __hip_bfloat16 Bs[3][16 * 512];   // 16 panels (256 cols x 32 k)

  const int tid  = threadIdx.x;
  const int lane = tid & 63;
  const int w    = tid >> 6;           // 0..7
  const int wm   = w >> 2, wn = w & 3; // wave tile 64x64
  const int quad = lane >> 4, m16 = lane & 15;

  const int nwg = gridDim.x;
  const int q8  = nwg >> 3, r8 = nwg & 7;
  const int xcd = blockIdx.x & 7, o8 = blockIdx.x >> 3;
  const int swz = (xcd < r8 ? xcd * (q8 + 1) : r8 * (q8 + 1) + (xcd - r8) * q8) + o8;
  const int bx = swz % nwg_x, by = swz / nwg_x;
  const int bm = by * 128, bn = bx * 256;

  const __hip_bfloat16* gA  = A  + (size_t)(bm + w * 16 + m16) * K + quad * 8;
  const __hip_bfloat16* gB0 = Bw + (size_t)(bn + (w * 2 + 0) * 16 + m16) * K + quad * 8;
  const __hip_bfloat16* gB1 = Bw + (size_t)(bn + (w * 2 + 1) * 16 + m16) * K + quad * 8;

  const int nt = K >> 5;

  async16(gA,       &As[0][w * 512]);
  async16(gB0,      &Bs[0][(w * 2 + 0) * 512]);
  async16(gB1,      &Bs[0][(w * 2 + 1) * 512]);
  async16(gA + 32,  &As[1][w * 512]);
  async16(gB0 + 32, &Bs[1][(w * 2 + 0) * 512]);
  async16(gB1 + 32, &Bs[1][(w * 2 + 1) * 512]);

  floatx4 acc[4][4] = {};
  const int fragoff = (quad * 16 + m16) * 8;

  int cur = 0, stg = 2;
  for (int t = 0; t < nt; ++t) {
    if (t < nt - 1) asm volatile("s_waitcnt vmcnt(3)" ::: "memory");
    else            asm volatile("s_waitcnt vmcnt(0)" ::: "memory");
    __builtin_amdgcn_s_barrier();
    __builtin_amdgcn_sched_barrier(0);

    const __hip_bfloat16* abase = &As[cur][0];
    const __hip_bfloat16* bbase = &Bs[cur][0];

    short8 a[4], b[4];
#pragma unroll
    for (int i = 0; i < 4; ++i) {
      a[i] = *(const short8*)(abase + (wm * 4 + i) * 512 + fragoff);
      b[i] = *(const short8*)(bbase + (wn * 4 + i) * 512 + fragoff);
    }
    if (t + 2 < nt) {
      const size_t ko = (size_t)(t + 2) * 32;
      async16(gA + ko,  &As[stg][w * 512]);
      async16(gB0 + ko, &Bs[stg][(w * 2 + 0) * 512]);
      async16(gB1 + ko, &Bs[stg][(w * 2 + 1) * 512]);
    }
    __builtin_amdgcn_s_setprio(1);
#pragma unroll
    for (int i = 0; i < 4; ++i)
#pragma unroll
      for (int j = 0; j < 4; ++j)
        acc[i][j] = __builtin_amdgcn_mfma_f32_16x16x32_bf16(a[i], b[j], acc[i][j], 0, 0, 0);
    __builtin_amdgcn_s_setprio(0);

    cur = (cur == 2) ? 0 : cur + 1;
    stg = (stg == 2) ? 0 : stg + 1;
  }

#pragma unroll
  for (int mi = 0; mi < 4; ++mi)
#pragma unroll
    for (int nj = 0; nj < 4; ++nj)
#pragma unroll
      for (int reg = 0; reg < 4; ++reg) {
        const int row = bm + wm * 64 + mi * 16 + quad * 4 + reg;
        const int col = bn + wn * 64 + nj * 16 + m16;
        Cout[(size_t)row * N + col] = acc[mi][nj][reg];
      }
}

// =====================================================================
// Head-fused flash attention, transpose-form, 32-row q-tiles.
// KEY-SPLIT waves: 8 waves = 4 heads x 2 key-halves (round-6 verified
// form; PV on 16x16x16_1k).
// =====================================================================
__global__ __launch_bounds__(512, 2) void flash_attn_t2(
    const __hip_bfloat16* __restrict__ qkv,  // [B*T][SQKV]
    const __hip_bfloat16* __restrict__ vt,   // [B][HKV][DH][T]
    __hip_bfloat16* __restrict__ ao) {       // [B*T][D]
  // [buf][ K: 0..8191 | V: 8192..16383 ]  (64 KiB total, reused as
  // fp32 scratch for the cross-wave reduction after the main loop)
  __shared__ __hip_bfloat16 KV[2][16384];

  const int tid = threadIdx.x, lane = tid & 63, w = tid >> 6;   // w 0..7
  const int quad = lane >> 4, m16 = lane & 15;

  const int bid = blockIdx.x;
  const int g = bid & 7;                    // (b,kvh) group -> XCD affinity
  const int b = g >> 2, kvh = g & 3;
  const int u = bid >> 3;                   // 0..63
  const int qt = 63 - u;                    // heavy first (LPT)
  const int hw = w & 3;                     // head-within-group
  const int khalf = w >> 2;                 // 0/1: which 32-key half
  const int h = kvh * 4 + hw;
  const int qRow0 = qt * 32;
  const int ktEnd = (qt >> 1) + 1;          // 1..32 slabs of 64 keys

  const size_t bT = (size_t)b * T_;

  // Q fragments (B-operand layout): 2 row-tiles x 4 dh-steps
  short8 qa[2][4];
#pragma unroll
  for (int qi = 0; qi < 2; qi++) {
    const __hip_bfloat16* qp = qkv + (bT + qRow0 + qi * 16 + m16) * SQKV + h * DH_;
#pragma unroll
    for (int ks = 0; ks < 4; ks++) qa[qi][ks] = *(const short8*)(qp + ks * 32 + quad * 8);
  }

  const short one = (short)0x3F80;
  const short4v ones4 = {one, one, one, one};

  // staging pointers: 8 waves x 2 issues cover the 16 panels of K and V
  const __hip_bfloat16* kptr[2];
  const __hip_bfloat16* vptr[2];
#pragma unroll
  for (int e = 0; e < 2; e++) {
    const int I = w * 2 + e;                 // 0..15
    const int panelK = I >> 2, kcK = (I & 3) * 4 + quad;
    kptr[e] = qkv + D_ + (bT + panelK * 16 + m16) * SQKV + kvh * DH_ + kcK * 8;
    const int panelV = I >> 1, tc = (I & 1) * 4 + quad;
    vptr[e] = vt + ((size_t)(b * HKV_ + kvh) * DH_ + panelV * 16 + m16) * T_ + tc * 8;
  }

  // prologue: stage slab 0 into buffer 0
#pragma unroll
  for (int e = 0; e < 2; e++) {
    const int I = w * 2 + e;
    async16(kptr[e], &KV[0][I * 512]);
    async16(vptr[e], &KV[0][8192 + I * 512]);
    kptr[e] += (size_t)64 * SQKV;
    vptr[e] += 64;
  }

  floatx4 ot[8][2] = {};   // partial O^T [dh-tile][qrow-tile]
  floatx4 lt[2] = {};      // partial l   [qrow-tile]

  for (int kt = 0; kt < ktEnd; kt++) {
    const int cur = kt & 1;
    __syncthreads();       // drains cur-slab loads; prev reads of nxt done
    if (kt + 1 < ktEnd) {
      const int nxt = cur ^ 1;
#pragma unroll
      for (int e = 0; e < 2; e++) {
        const int I = w * 2 + e;
        async16(kptr[e], &KV[nxt][I * 512]);
        async16(vptr[e], &KV[nxt][8192 + I * 512]);
        kptr[e] += (size_t)64 * SQKV;
        vptr[e] += 64;
      }
    }

    const bool last = (kt == ktEnd - 1);
    // qt even: khalf=1 half of the diagonal slab is fully masked -> skip
    if (last && khalf == 1 && ((qt & 1) == 0)) continue;

    // ---- S^T = K Q^T  (this wave's 32 keys x 32 qrows) ----
    floatx4 st[2][2] = {};  // [ki=key-16-tile within half][qi]
#pragma unroll
    for (int ki = 0; ki < 2; ki++) {
      const int kg = khalf * 2 + ki;        // global key-16-tile 0..3
#pragma unroll
      for (int ks = 0; ks < 4; ks++) {
        const int unit = kg * 256 + (ks * 4 + quad) * 16 + m16;
        const short8 kf = *(const short8*)&KV[cur][unit * 8];
#pragma unroll
        for (int qi = 0; qi < 2; qi++)
          st[ki][qi] = __builtin_amdgcn_mfma_f32_16x16x32_bf16(kf, qa[qi][ks],
                                                               st[ki][qi], 0, 0, 0);
      }
    }

    // ---- causal mask: only the matching 32-range needs it ----
    if (last && khalf == (qt & 1)) {
#pragma unroll
      for (int ki = 0; ki < 2; ki++)
#pragma unroll
        for (int qi = 0; qi < 2; qi++) {
          const int rowg = qRow0 + qi * 16 + m16;
#pragma unroll
          for (int reg = 0; reg < 4; reg++) {
            const int keyg = kt * 64 + khalf * 32 + ki * 16 + quad * 4 + reg;
            if (keyg > rowg) st[ki][qi][reg] = -1e30f;
          }
        }
    }

    // ---- P^T = exp(S^T), packed: C-tile == 16x16x16 B-frag ----
    short4v pf[2][2];
#pragma unroll
    for (int ki = 0; ki < 2; ki++)
#pragma unroll
      for (int qi = 0; qi < 2; qi++) {
        short4v t;
#pragma unroll
        for (int reg = 0; reg < 4; reg++) t[reg] = bf16b(__expf(st[ki][qi][reg]));
        pf[ki][qi] = t;
      }

    // ---- O^T += V^T P^T ; l += ones P^T  (partial over this key half) ----
#pragma unroll
    for (int mi = 0; mi < 8; mi++)
#pragma unroll
      for (int ki = 0; ki < 2; ki++) {
        const int kg = khalf * 2 + ki;
        const int unit = mi * 128 + (kg * 2 + (quad >> 1)) * 16 + m16;
        const short4v vf = *(const short4v*)&KV[cur][8192 + unit * 8 + (quad & 1) * 4];
#pragma unroll
        for (int qi = 0; qi < 2; qi++)
          ot[mi][qi] = __builtin_amdgcn_mfma_f32_16x16x16bf16_1k(vf, pf[ki][qi],
                                                                 ot[mi][qi], 0, 0, 0);
      }
#pragma unroll
    for (int ki = 0; ki < 2; ki++)
#pragma unroll
      for (int qi = 0; qi < 2; qi++)
        lt[qi] = __builtin_amdgcn_mfma_f32_16x16x16bf16_1k(ones4, pf[ki][qi],
                                                           lt[qi], 0, 0, 0);
  }

  // ---- cross-wave reduction (khalf pairs) via retired KV buffers ----
  floatx4* scr = (floatx4*)&KV[0][0];   // 4096 slots of 16B
  __syncthreads();                      // all slab reads of KV done
  if (khalf == 1) {                     // round 1: mi 0..5
#pragma unroll
    for (int mi = 0; mi < 6; mi++)
#pragma unroll
      for (int qi = 0; qi < 2; qi++)
        scr[((hw * 6 + mi) * 2 + qi) * 64 + lane] = ot[mi][qi];
  }
  __syncthreads();
  if (khalf == 0) {
#pragma unroll
    for (int mi = 0; mi < 6; mi++)
#pragma unroll
      for (int qi = 0; qi < 2; qi++)
        ot[mi][qi] += scr[((hw * 6 + mi) * 2 + qi) * 64 + lane];
  }
  __syncthreads();
  if (khalf == 1) {                     // round 2: mi 6..7 + lt
#pragma unroll
    for (int j = 0; j < 2; j++)
#pragma unroll
      for (int qi = 0; qi < 2; qi++)
        scr[((hw * 2 + j) * 2 + qi) * 64 + lane] = ot[6 + j][qi];
#pragma unroll
    for (int qi = 0; qi < 2; qi++)
      scr[1024 + (hw * 2 + qi) * 64 + lane] = lt[qi];
  }
  __syncthreads();
  if (khalf == 0) {
#pragma unroll
    for (int j = 0; j < 2; j++)
#pragma unroll
      for (int qi = 0; qi < 2; qi++)
        ot[6 + j][qi] += scr[((hw * 2 + j) * 2 + qi) * 64 + lane];
#pragma unroll
    for (int qi = 0; qi < 2; qi++)
      lt[qi] += scr[1024 + (hw * 2 + qi) * 64 + lane];

    // ---- epilogue: O^T C-layout -> packed b64 row-stores ----
#pragma unroll
    for (int qi = 0; qi < 2; qi++) {
      const float inv = 1.0f / lt[qi][0];   // all regs equal = l[qrow]
      const size_t gr = (bT + qRow0 + qi * 16 + m16) * D_ + h * DH_;
#pragma unroll
      for (int mi = 0; mi < 8; mi++) {
        short4v o;
#pragma unroll
        for (int reg = 0; reg < 4; reg++) o[reg] = bf16b(ot[mi][qi][reg] * inv);
        *(short4v*)&ao[gr + mi * 16 + quad * 4] = o;
      }
    }
  }
}

// =====================================================================
// Launch
// =====================================================================
extern "C" void kernel_launch(void* const* d_in, const int* in_sizes, int n_in,
                              void* d_out, int out_size, void* d_ws, size_t ws_size,
                              hipStream_t stream) {
  const float* x    = (const float*)d_in[0];
  const float* cosT = (const float*)d_in[1];
  const float* sinT = (const float*)d_in[2];
  const float* Wq   = (const float*)d_in[3];
  const float* Wk   = (const float*)d_in[4];
  const float* Wv   = (const float*)d_in[5];
  const float* Wo   = (const float*)d_in[6];
  const float* temp = (const float*)d_in[7];
  float* out = (float*)d_out;

  const int M = B_ * T_;                     // 4096
  const size_t XN   = (size_t)M * D_;
  const size_t WQN  = (size_t)D_ * D_;
  const size_t WKN  = (size_t)KD_ * D_;
  const size_t QKVN = (size_t)M * SQKV;
  const size_t KN   = (size_t)M * KD_;

  __hip_bfloat16* ws = (__hip_bfloat16*)d_ws;
  __hip_bfloat16* xb    = ws;  ws += XN;
  __hip_bfloat16* wqkvb = ws;  ws += WQN + 2 * WKN;
  __hip_bfloat16* wob   = ws;  ws += WQN;
  __hip_bfloat16* qkvb  = ws;  ws += QKVN;
  __hip_bfloat16* vtb   = ws;  ws += KN;
  __hip_bfloat16* aob   = ws;  ws += XN;

  dim3 blk(256);

  ConvArgs ca;
  ca.src[0] = x;  ca.dst[0] = xb;                  ca.n[0] = (int)XN;
  ca.src[1] = Wq; ca.dst[1] = wqkvb;               ca.n[1] = (int)WQN;
  ca.src[2] = Wk; ca.dst[2] = wqkvb + WQN;         ca.n[2] = (int)WKN;
  ca.src[3] = Wv; ca.dst[3] = wqkvb + WQN + WKN;   ca.n[3] = (int)WKN;
  ca.src[4] = Wo; ca.dst[4] = wob;                 ca.n[4] = (int)WQN;
  conv_bf16<<<dim3(4096, 5), blk, 0, stream>>>(ca);

  const float inv_sqrt_dh = 1.0f / sqrtf((float)DH_);

  // fused QKV projection + RoPE + scaling (256x192 tiles, 256 blocks =
  // one full uniform CU round); v-col frags -> vtb transposed
  gemm_192<2><<<dim3((SQKV / 192) * (M / 256)), dim3(512), 0, stream>>>(
      xb, wqkvb, qkvb, vtb, cosT, sinT, temp, inv_sqrt_dh, M, SQKV, D_, SQKV / 192);

  // 512 blocks x 512 threads (8 waves: 4 heads x 2 key-halves)
  flash_attn_t2<<<512, dim3(512), 0, stream>>>(qkvb, vtb, aob);

  // output projection (128x256 tiles, 256 blocks = full CU fill)
  gemm_k1<<<dim3((D_ / 256) * (M / 128)), dim3(512), 0, stream>>>(
      aob, wob, out, M, D_, D_, D_ / 256);
}